// Round 3
// baseline (280.387 us; speedup 1.0000x reference)
//
#include <hip/hip_runtime.h>
#include <hip/hip_bf16.h>

#define N_NODES 50000
#define N_EDGES 800000
#define NBK 391          // ceil(50000/128) row buckets of 128 rows
#define BCAP 2560        // slab capacity per bucket (mean 2048 + 11 sigma)
#define PADSLACK 896     // max pad per bucket: 128 rows x 7

static inline int cdiv(int a, int b) { return (a + b - 1) / b; }

typedef __attribute__((ext_vector_type(8))) short short8;
typedef __attribute__((ext_vector_type(4))) float f32x4;

__device__ __forceinline__ float b2f(unsigned short u) {
    union { unsigned int i; float f; } c;
    c.i = ((unsigned int)u) << 16;
    return c.f;
}
__device__ __forceinline__ unsigned short f2bb(float f) {
    __hip_bfloat16 h = __float2bfloat16(f);
    return *(unsigned short*)&h;
}

__device__ __forceinline__ void pack_one(const float* __restrict__ W,
                                         __hip_bfloat16* __restrict__ out,
                                         int K, int N, int t) {
    int lane = t & 63;
    int kc = (t >> 6) % (K / 32);
    int nt = (t >> 6) / (K / 32);
    int kbase = kc * 32 + (lane >> 4) * 8;
    int col = nt * 16 + (lane & 15);
    __hip_bfloat16* dst = out + (size_t)t * 8;
#pragma unroll
    for (int j = 0; j < 8; ++j)
        dst[j] = __float2bfloat16(W[(size_t)(kbase + j) * N + col]);
}

// ---------------- stage1: binA (0..195) + gemm1 (196..977) + packs (978..1021) ----------------
__global__ __launch_bounds__(256)
void stage1_kernel(const int* __restrict__ row, const int* __restrict__ col,
                   const float* __restrict__ vals, int* __restrict__ bcursor,
                   int2* __restrict__ tmp, int E,
                   const float* __restrict__ x, __hip_bfloat16* __restrict__ support,
                   int M,
                   const float* __restrict__ W1, const float* __restrict__ W2,
                   const float* __restrict__ W3, const float* __restrict__ fcW1,
                   const float* __restrict__ fcW2,
                   __hip_bfloat16* __restrict__ pW2, __hip_bfloat16* __restrict__ pW3,
                   __hip_bfloat16* __restrict__ pfcW1, __hip_bfloat16* __restrict__ pfcW2) {
    __shared__ unsigned short As[64][136];
    __shared__ int hist[NBK];
    __shared__ int base[NBK];
    const int b = blockIdx.x;
    const int tid = threadIdx.x;

    if (b < 196) {
        const int CH = 4096;
        int e0 = b * CH;
        for (int i = tid; i < NBK; i += 256) hist[i] = 0;
        __syncthreads();
        for (int i = tid; i < CH; i += 256) {
            int e = e0 + i;
            if (e < E) atomicAdd(&hist[row[e] >> 7], 1);
        }
        __syncthreads();
        for (int i = tid; i < NBK; i += 256) {
            int c = hist[i];
            base[i] = (c > 0) ? (i * BCAP + atomicAdd(&bcursor[i], c)) : 0;
            hist[i] = 0;
        }
        __syncthreads();
        for (int i = tid; i < CH; i += 256) {
            int e = e0 + i;
            if (e < E) {
                int r = row[e];
                int bk = r >> 7;
                int rk = atomicAdd(&hist[bk], 1);
                tmp[base[bk] + rk] = make_int2(((r & 127) << 16) | col[e],
                                               __float_as_int(vals[e]));
            }
        }
        return;
    }

    if (b < 978) {
        const int wave = tid >> 6;
        const int lane = tid & 63;
        const int ln15 = lane & 15;
        const int quad = lane >> 4;
        const int m0 = (b - 196) * 64;

        short8 bfr[4][2];
#pragma unroll
        for (int kc = 0; kc < 4; ++kc)
#pragma unroll
            for (int h = 0; h < 2; ++h)
#pragma unroll
                for (int j = 0; j < 8; ++j)
                    bfr[kc][h][j] = (short)f2bb(
                        W1[(size_t)(kc * 32 + quad * 8 + j) * 128 + (wave * 2 + h) * 16 + ln15]);

#pragma unroll
        for (int i = 0; i < 4; ++i) {
            int idx = tid + i * 256;
            int r = idx >> 4;
            int c8 = (idx & 15) * 8;
            uint4 pk = {0, 0, 0, 0};
            if (m0 + r < M) {
                const float* src = &x[(size_t)(m0 + r) * 128 + c8];
                float4 a = *(const float4*)src;
                float4 bq = *(const float4*)(src + 4);
                pk.x = f2bb(a.x) | ((unsigned int)f2bb(a.y) << 16);
                pk.y = f2bb(a.z) | ((unsigned int)f2bb(a.w) << 16);
                pk.z = f2bb(bq.x) | ((unsigned int)f2bb(bq.y) << 16);
                pk.w = f2bb(bq.z) | ((unsigned int)f2bb(bq.w) << 16);
            }
            *(uint4*)&As[r][c8] = pk;
        }
        __syncthreads();

        f32x4 acc[4][2];
#pragma unroll
        for (int s = 0; s < 4; ++s)
#pragma unroll
            for (int h = 0; h < 2; ++h) acc[s][h] = (f32x4){0.f, 0.f, 0.f, 0.f};
#pragma unroll
        for (int kc = 0; kc < 4; ++kc) {
            short8 af[4];
#pragma unroll
            for (int s = 0; s < 4; ++s)
                af[s] = *(const short8*)&As[s * 16 + ln15][kc * 32 + quad * 8];
#pragma unroll
            for (int s = 0; s < 4; ++s)
#pragma unroll
                for (int h = 0; h < 2; ++h)
                    acc[s][h] = __builtin_amdgcn_mfma_f32_16x16x32_bf16(
                        af[s], bfr[kc][h], acc[s][h], 0, 0, 0);
        }
#pragma unroll
        for (int s = 0; s < 4; ++s)
#pragma unroll
            for (int h = 0; h < 2; ++h) {
                int cl = (wave * 2 + h) * 16 + ln15;
#pragma unroll
                for (int r = 0; r < 4; ++r) {
                    int rw = m0 + s * 16 + quad * 4 + r;
                    if (rw < M)
                        support[(size_t)rw * 128 + cl] = __float2bfloat16(acc[s][h][r]);
                }
            }
        return;
    }

    int pb = b - 978;
    if (pb < 8)       pack_one(W2,  pW2,  128, 128, pb * 256 + tid);
    else if (pb < 16) pack_one(W3,  pW3,  128, 128, (pb - 8) * 256 + tid);
    else if (pb < 40) pack_one(fcW1, pfcW1, 384, 128, (pb - 16) * 256 + tid);
    else              pack_one(fcW2, pfcW2, 128, 64, (pb - 40) * 256 + tid);
}

// ---------------- CSR: per-bucket counting sort w/ 8-padding; fused bucket scan ----------------
__global__ __launch_bounds__(256)
void binB_kernel(const int2* __restrict__ tmp, const int* __restrict__ bcursor,
                 int2* __restrict__ rowrange, int2* __restrict__ epack, int N) {
    int b = blockIdx.x;
    int r0 = b << 7;
    int nr = N - r0; if (nr > 128) nr = 128;
    __shared__ int cnt[128];
    __shared__ int cur[128];
    __shared__ int rpos[128];
    __shared__ int red[256];
    int t = threadIdx.x;
    // fused exclusive scan: red[0] = sum_{i<b} bcursor[i]
    int partial = 0;
    for (int i = t; i < b; i += 256) partial += bcursor[i];
    red[t] = partial;
    if (t < 128) cnt[t] = 0;
    __syncthreads();
    for (int off = 128; off > 0; off >>= 1) {
        if (t < off) red[t] += red[t + off];
        __syncthreads();
    }
    int slab = b * BCAP;
    int send = slab + bcursor[b];
    for (int i = slab + t; i < send; i += 256)
        atomicAdd(&cnt[tmp[i].x >> 16], 1);
    __syncthreads();
    int rcnt = (t < 128) ? cnt[t] : 0;
    int pc = (rcnt + 7) & ~7;
    if (t < 128) cur[t] = pc;
    __syncthreads();
    for (int off = 1; off < 128; off <<= 1) {
        int u = (t >= off && t < 128) ? cur[t - off] : 0;
        __syncthreads();
        if (t < 128) cur[t] += u;
        __syncthreads();
    }
    int obase = red[0] + b * PADSLACK;
    if (t < 128) {
        int pos = obase + cur[t] - pc;
        rpos[t] = pos;
        cur[t] = pos;
        if (t < nr) rowrange[r0 + t] = make_int2(pos, pos + pc);
    }
    __syncthreads();
    for (int i = slab + t; i < send; i += 256) {
        int2 v = tmp[i];
        int rl = v.x >> 16;
        int c = v.x & 0xffff;
        int pos = atomicAdd(&cur[rl], 1);
        epack[pos] = make_int2(c, v.y);
    }
    if (t < 128) {
        int rc = rcnt;
        int pos = rpos[t];
#pragma unroll 1
        for (int i = pos + rc; i < pos + pc; ++i)
            epack[i] = make_int2(0, 0);
    }
}

// ---------------- shared aggregation helper ----------------
__device__ __forceinline__ void accum8(float* acc, long long e, uint4 u) {
    float f = __int_as_float((int)(e >> 32));
    acc[0] += f * b2f((unsigned short)(u.x & 0xffff));
    acc[1] += f * b2f((unsigned short)(u.x >> 16));
    acc[2] += f * b2f((unsigned short)(u.y & 0xffff));
    acc[3] += f * b2f((unsigned short)(u.y >> 16));
    acc[4] += f * b2f((unsigned short)(u.z & 0xffff));
    acc[5] += f * b2f((unsigned short)(u.z >> 16));
    acc[6] += f * b2f((unsigned short)(u.w & 0xffff));
    acc[7] += f * b2f((unsigned short)(u.w >> 16));
}

// Aggregate one node's row (128 cols as 4 groups x 16 lanes x 8 cols), returning
// per-lane 8 partial cols; wave split 4 groups of 16 lanes, dwordx4 gathers.
__device__ __forceinline__ void agg_node(const long long* __restrict__ ep,
                                         const __hip_bfloat16* __restrict__ support,
                                         int p, int end, int g, int j, float* acc) {
#pragma unroll
    for (int k = 0; k < 8; ++k) acc[k] = 0.f;
    long long e0 = 0, e1 = 0;
    uint4 u0 = {0, 0, 0, 0}, u1 = {0, 0, 0, 0};
    bool have = false;
    if (p < end) {
        e0 = ep[p + g];
        e1 = ep[p + 4 + g];
        u0 = *(const uint4*)&support[(size_t)(unsigned int)(e0 & 0xffffffffu) * 128 + j * 8];
        u1 = *(const uint4*)&support[(size_t)(unsigned int)(e1 & 0xffffffffu) * 128 + j * 8];
        p += 8;
        have = true;
    }
    while (p < end) {
        long long f0 = ep[p + g];
        long long f1 = ep[p + 4 + g];
        uint4 w0 = *(const uint4*)&support[(size_t)(unsigned int)(f0 & 0xffffffffu) * 128 + j * 8];
        uint4 w1 = *(const uint4*)&support[(size_t)(unsigned int)(f1 & 0xffffffffu) * 128 + j * 8];
        accum8(acc, e0, u0);
        accum8(acc, e1, u1);
        e0 = f0; u0 = w0; e1 = f1; u1 = w1;
        p += 8;
    }
    if (have) {
        accum8(acc, e0, u0);
        accum8(acc, e1, u1);
    }
    // combine the 4 edge-group partials: lanes {j, j+16, j+32, j+48} share cols
#pragma unroll
    for (int k = 0; k < 8; ++k) {
        acc[k] += __shfl_xor(acc[k], 16);
        acc[k] += __shfl_xor(acc[k], 32);
    }
}

// ---------------- fused SpMM (64 rows/block, 8 waves x 8 nodes) + next-layer GEMM ----------------
__global__ __launch_bounds__(512, 4)
void spmm_gemm_kernel(const int2* __restrict__ rowrange,
                      const int2* __restrict__ epack,
                      const __hip_bfloat16* __restrict__ support,
                      const float* __restrict__ bias,
                      __hip_bfloat16* __restrict__ gout,      // featb slice, ld 384
                      const __hip_bfloat16* __restrict__ pW,  // next layer packed W
                      __hip_bfloat16* __restrict__ Cout,      // next support, ld 128
                      int N) {
    __shared__ unsigned short As[64][136];
    const int tid = threadIdx.x;
    const int wv = tid >> 6;       // 0..7
    const int l = tid & 63;
    const int g = l >> 4;
    const int j = l & 15;
    const int m0 = blockIdx.x * 64;
    const long long* ep = (const long long*)epack;
    float4 b0 = *(const float4*)&bias[j * 8];
    float4 b1 = *(const float4*)&bias[j * 8 + 4];

    for (int i = 0; i < 8; ++i) {
        int node = m0 + wv * 8 + i;
        if (node >= N) {
            if (g == 0) *(uint4*)&As[wv * 8 + i][j * 8] = (uint4){0, 0, 0, 0};
            continue;
        }
        int2 rr = rowrange[node];
        float acc[8];
        agg_node(ep, support, rr.x, rr.y, g, j, acc);
        if (g == 0) {
            unsigned int q0 = (unsigned int)f2bb(fmaxf(acc[0] + b0.x, 0.f))
                            | ((unsigned int)f2bb(fmaxf(acc[1] + b0.y, 0.f)) << 16);
            unsigned int q1 = (unsigned int)f2bb(fmaxf(acc[2] + b0.z, 0.f))
                            | ((unsigned int)f2bb(fmaxf(acc[3] + b0.w, 0.f)) << 16);
            unsigned int q2 = (unsigned int)f2bb(fmaxf(acc[4] + b1.x, 0.f))
                            | ((unsigned int)f2bb(fmaxf(acc[5] + b1.y, 0.f)) << 16);
            unsigned int q3 = (unsigned int)f2bb(fmaxf(acc[6] + b1.z, 0.f))
                            | ((unsigned int)f2bb(fmaxf(acc[7] + b1.w, 0.f)) << 16);
            uint4 st = {q0, q1, q2, q3};
            *(uint4*)&As[wv * 8 + i][j * 8] = st;
            *(uint4*)&gout[(size_t)(m0 + wv * 8 + i) * 384 + j * 8] = st;
        }
    }
    __syncthreads();

    // ---- MFMA: Cout[m0:m0+64] = g @ W ; 8 waves, wave wv owns 16-col block wv ----
    const int ln15 = l & 15;
    const int quad = l >> 4;
    f32x4 acc2[4];
#pragma unroll
    for (int s = 0; s < 4; ++s) acc2[s] = (f32x4){0.f, 0.f, 0.f, 0.f};
#pragma unroll
    for (int kc = 0; kc < 4; ++kc) {
        short8 af[4];
#pragma unroll
        for (int s = 0; s < 4; ++s)
            af[s] = *(const short8*)&As[s * 16 + ln15][kc * 32 + quad * 8];
        short8 bf = *(const short8*)&pW[((size_t)(wv * 4 + kc) * 64 + l) * 8];
#pragma unroll
        for (int s = 0; s < 4; ++s)
            acc2[s] = __builtin_amdgcn_mfma_f32_16x16x32_bf16(af[s], bf, acc2[s], 0, 0, 0);
    }
    {
        int cl = wv * 16 + ln15;
#pragma unroll
        for (int s = 0; s < 4; ++s)
#pragma unroll
            for (int r = 0; r < 4; ++r) {
                int rw = m0 + s * 16 + quad * 4 + r;
                if (rw < N)
                    Cout[(size_t)rw * 128 + cl] = __float2bfloat16(acc2[s][r]);
            }
    }
}

// ---------------- fused SpMM (g3) + FC head, 512 threads ----------------
__global__ __launch_bounds__(512, 4)
void spmm_fc_kernel(const int2* __restrict__ rowrange,
                    const int2* __restrict__ epack,
                    const __hip_bfloat16* __restrict__ support,
                    const float* __restrict__ bias,           // b3
                    const __hip_bfloat16* __restrict__ featb, // g1|g2 (cols 0..255), ld 384
                    const __hip_bfloat16* __restrict__ pfcW1,
                    const float* __restrict__ fcb1,
                    const __hip_bfloat16* __restrict__ pfcW2,
                    const float* __restrict__ fcb2,
                    const float* __restrict__ fcW3, const float* __restrict__ fcb3,
                    float* __restrict__ out, int N) {
    __shared__ unsigned short As[64][136];
    __shared__ float w3s[128];
    __shared__ float b3s[2];
    const int tid = threadIdx.x;
    const int wv = tid >> 6;       // 0..7
    const int l = tid & 63;
    const int g = l >> 4;
    const int j = l & 15;
    const int m0 = blockIdx.x * 64;
    const long long* ep = (const long long*)epack;
    if (tid < 128) w3s[tid] = fcW3[tid];
    if (tid < 2) b3s[tid] = fcb3[tid];
    float4 b0 = *(const float4*)&bias[j * 8];
    float4 b1 = *(const float4*)&bias[j * 8 + 4];

    // ---- aggregate g3 into As only (g3 has no other consumer) ----
    for (int i = 0; i < 8; ++i) {
        int node = m0 + wv * 8 + i;
        if (node >= N) {
            if (g == 0) *(uint4*)&As[wv * 8 + i][j * 8] = (uint4){0, 0, 0, 0};
            continue;
        }
        int2 rr = rowrange[node];
        float acc[8];
        agg_node(ep, support, rr.x, rr.y, g, j, acc);
        if (g == 0) {
            unsigned int q0 = (unsigned int)f2bb(fmaxf(acc[0] + b0.x, 0.f))
                            | ((unsigned int)f2bb(fmaxf(acc[1] + b0.y, 0.f)) << 16);
            unsigned int q1 = (unsigned int)f2bb(fmaxf(acc[2] + b0.z, 0.f))
                            | ((unsigned int)f2bb(fmaxf(acc[3] + b0.w, 0.f)) << 16);
            unsigned int q2 = (unsigned int)f2bb(fmaxf(acc[4] + b1.x, 0.f))
                            | ((unsigned int)f2bb(fmaxf(acc[5] + b1.y, 0.f)) << 16);
            unsigned int q3 = (unsigned int)f2bb(fmaxf(acc[6] + b1.z, 0.f))
                            | ((unsigned int)f2bb(fmaxf(acc[7] + b1.w, 0.f)) << 16);
            uint4 st = {q0, q1, q2, q3};
            *(uint4*)&As[wv * 8 + i][j * 8] = st;
        }
    }
    __syncthreads();

    // ---- fc1: feat @ fcW1 over kb in order {2 (g3, already in As), 0, 1} ----
    const int ln15 = l & 15;
    const int quad = l >> 4;
    f32x4 acc[4];
#pragma unroll
    for (int s = 0; s < 4; ++s) acc[s] = (f32x4){0.f, 0.f, 0.f, 0.f};
#pragma unroll
    for (int step = 0; step < 3; ++step) {
        const int kb = (step == 0) ? 2 : (step - 1);
        if (step != 0) {
            __syncthreads();   // previous MFMAs done reading As
#pragma unroll
            for (int i = 0; i < 2; ++i) {
                int idx = tid + i * 512;
                int r = idx >> 4;
                int c8 = (idx & 15) * 8;
                uint4 v = *(const uint4*)&featb[(size_t)(m0 + r) * 384 + kb * 128 + c8];
                *(uint4*)&As[r][c8] = v;
            }
            __syncthreads();
        }
#pragma unroll
        for (int kc = 0; kc < 4; ++kc) {
            short8 af[4];
#pragma unroll
            for (int s = 0; s < 4; ++s)
                af[s] = *(const short8*)&As[s * 16 + ln15][kc * 32 + quad * 8];
            int kcg = kb * 4 + kc;
            short8 bf = *(const short8*)&pfcW1[((size_t)(wv * 12 + kcg) * 64 + l) * 8];
#pragma unroll
            for (int s = 0; s < 4; ++s)
                acc[s] = __builtin_amdgcn_mfma_f32_16x16x32_bf16(af[s], bf, acc[s], 0, 0, 0);
        }
    }
    __syncthreads();
    {
        int col = wv * 16 + ln15;
        float bv = fcb1[col];
#pragma unroll
        for (int s = 0; s < 4; ++s)
#pragma unroll
            for (int r = 0; r < 4; ++r) {
                int row = s * 16 + quad * 4 + r;
                As[row][col] = f2bb(fmaxf(acc[s][r] + bv, 0.f));
            }
    }
    __syncthreads();

    // ---- fc2: 128 -> 64, waves 0..3 ----
    if (wv < 4) {
        f32x4 acc2[4];
#pragma unroll
        for (int s = 0; s < 4; ++s) acc2[s] = (f32x4){0.f, 0.f, 0.f, 0.f};
#pragma unroll
        for (int kc = 0; kc < 4; ++kc) {
            short8 af[4];
#pragma unroll
            for (int s = 0; s < 4; ++s)
                af[s] = *(const short8*)&As[s * 16 + ln15][kc * 32 + quad * 8];
            short8 bfw = *(const short8*)&pfcW2[((size_t)(wv * 4 + kc) * 64 + l) * 8];
#pragma unroll
            for (int s = 0; s < 4; ++s)
                acc2[s] = __builtin_amdgcn_mfma_f32_16x16x32_bf16(af[s], bfw, acc2[s], 0, 0, 0);
        }
        __syncthreads();
        int col2 = wv * 16 + ln15;
        float bv = fcb2[col2];
#pragma unroll
        for (int s = 0; s < 4; ++s)
#pragma unroll
            for (int r = 0; r < 4; ++r) {
                int row = s * 16 + quad * 4 + r;
                As[row][col2] = f2bb(fmaxf(acc2[s][r] + bv, 0.f));
            }
    } else {
        __syncthreads();
    }
    __syncthreads();

    // ---- fc3: 64 -> 2 ----
    if (tid < 128) {
        int row = tid >> 1, cls = tid & 1;
        int grow = m0 + row;
        if (grow < N) {
            float a = b3s[cls];
#pragma unroll
            for (int k = 0; k < 64; ++k)
                a += b2f(As[row][k]) * w3s[k * 2 + cls];
            out[(size_t)grow * 2 + cls] = a;
        }
    }
}

extern "C" void kernel_launch(void* const* d_in, const int* in_sizes, int n_in,
                              void* d_out, int out_size, void* d_ws, size_t ws_size,
                              hipStream_t stream) {
    const int*   adj_row  = (const int*)d_in[0];
    const int*   adj_col  = (const int*)d_in[1];
    const float* adj_vals = (const float*)d_in[2];
    const float* x        = (const float*)d_in[3];
    const float* W1   = (const float*)d_in[5];
    const float* b1   = (const float*)d_in[6];
    const float* W2   = (const float*)d_in[7];
    const float* b2   = (const float*)d_in[8];
    const float* W3   = (const float*)d_in[9];
    const float* b3   = (const float*)d_in[10];
    const float* fcW1 = (const float*)d_in[11];
    const float* fcb1 = (const float*)d_in[12];
    const float* fcW2 = (const float*)d_in[13];
    const float* fcb2 = (const float*)d_in[14];
    const float* fcW3 = (const float*)d_in[15];
    const float* fcb3 = (const float*)d_in[16];
    float* out = (float*)d_out;

    const int N = N_NODES, E = N_EDGES;
    const int Mpad = 50048;
    const int EPAD = E + NBK * PADSLACK + 64;   // padded edge capacity

    char* p = (char*)d_ws;
    auto alloc = [&](size_t bytes) {
        char* q = p;
        p += (bytes + 255) & ~(size_t)255;
        return q;
    };
    __hip_bfloat16* featb    = (__hip_bfloat16*)alloc((size_t)Mpad * 384 * 2); // g1|g2|(unused g3)
    __hip_bfloat16* supportb = (__hip_bfloat16*)alloc((size_t)Mpad * 128 * 2);
    __hip_bfloat16* supportc = (__hip_bfloat16*)alloc((size_t)Mpad * 128 * 2);
    __hip_bfloat16* pW2   = (__hip_bfloat16*)alloc(16384 * 2);
    __hip_bfloat16* pW3   = (__hip_bfloat16*)alloc(16384 * 2);
    __hip_bfloat16* pfcW1 = (__hip_bfloat16*)alloc(49152 * 2);
    __hip_bfloat16* pfcW2 = (__hip_bfloat16*)alloc(8192 * 2);
    int2*  rowrange  = (int2*)alloc((size_t)(N + 1) * 8);
    int*   bcursor   = (int*)alloc((size_t)NBK * 4);
    int2*  epack     = (int2*)alloc((size_t)EPAD * 8);
    int2*  tmp       = (int2*)alloc((size_t)NBK * BCAP * 8);

    // ---- stage1: binA + gemm1 + weight packs in one launch ----
    hipMemsetAsync(bcursor, 0, (size_t)NBK * 4, stream);
    stage1_kernel<<<1022, 256, 0, stream>>>(adj_row, adj_col, adj_vals, bcursor, tmp, E,
                                            x, supportb, N,
                                            W1, W2, W3, fcW1, fcW2,
                                            pW2, pW3, pfcW1, pfcW2);
    binB_kernel<<<NBK, 256, 0, stream>>>(tmp, bcursor, rowrange, epack, N);

    const int fgrid = cdiv(N, 64);

    // ---- F1: agg(support1)->g1 (featb) + gemm2 -> supportc ----
    spmm_gemm_kernel<<<fgrid, 512, 0, stream>>>(rowrange, epack, supportb, b1,
                                                featb + 0, pW2, supportc, N);
    // ---- F2: agg(support2)->g2 (featb+128) + gemm3 -> supportb ----
    spmm_gemm_kernel<<<fgrid, 512, 0, stream>>>(rowrange, epack, supportc, b2,
                                                featb + 128, pW3, supportb, N);
    // ---- F3: agg(support3)->g3 (LDS only) + FC head -> out ----
    spmm_fc_kernel<<<fgrid, 512, 0, stream>>>(rowrange, epack, supportb, b3,
                                              featb, pfcW1, fcb1, pfcW2, fcb2,
                                              fcW3, fcb3, out, N);
}

// Round 4
// 250.407 us; speedup vs baseline: 1.1197x; 1.1197x over previous
//
#include <hip/hip_runtime.h>
#include <hip/hip_bf16.h>

#define N_NODES 50000
#define N_EDGES 800000
#define NBK 391          // ceil(50000/128) row buckets of 128 rows
#define BCAP 2560        // slab capacity per bucket (mean 2048 + 11 sigma)
#define PADSLACK 896     // max pad per bucket: 128 rows x 7

static inline int cdiv(int a, int b) { return (a + b - 1) / b; }

typedef __attribute__((ext_vector_type(8))) short short8;
typedef __attribute__((ext_vector_type(4))) float f32x4;

__device__ __forceinline__ float b2f(unsigned short u) {
    union { unsigned int i; float f; } c;
    c.i = ((unsigned int)u) << 16;
    return c.f;
}
__device__ __forceinline__ unsigned short f2bb(float f) {
    __hip_bfloat16 h = __float2bfloat16(f);
    return *(unsigned short*)&h;
}

__device__ __forceinline__ void pack_one(const float* __restrict__ W,
                                         __hip_bfloat16* __restrict__ out,
                                         int K, int N, int t) {
    int lane = t & 63;
    int kc = (t >> 6) % (K / 32);
    int nt = (t >> 6) / (K / 32);
    int kbase = kc * 32 + (lane >> 4) * 8;
    int col = nt * 16 + (lane & 15);
    __hip_bfloat16* dst = out + (size_t)t * 8;
#pragma unroll
    for (int j = 0; j < 8; ++j)
        dst[j] = __float2bfloat16(W[(size_t)(kbase + j) * N + col]);
}

// ---------------- stage1: binA (0..195) + gemm1 (196..977) + packs (978..1021) ----------------
__global__ __launch_bounds__(256)
void stage1_kernel(const int* __restrict__ row, const int* __restrict__ col,
                   const float* __restrict__ vals, int* __restrict__ bcursor,
                   int2* __restrict__ tmp, int E,
                   const float* __restrict__ x, __hip_bfloat16* __restrict__ support,
                   int M,
                   const float* __restrict__ W1, const float* __restrict__ W2,
                   const float* __restrict__ W3, const float* __restrict__ fcW1,
                   const float* __restrict__ fcW2,
                   __hip_bfloat16* __restrict__ pW2, __hip_bfloat16* __restrict__ pW3,
                   __hip_bfloat16* __restrict__ pfcW1, __hip_bfloat16* __restrict__ pfcW2) {
    __shared__ unsigned short As[64][136];
    __shared__ int hist[NBK];
    __shared__ int base[NBK];
    const int b = blockIdx.x;
    const int tid = threadIdx.x;

    if (b < 196) {
        const int CH = 4096;
        int e0 = b * CH;
        for (int i = tid; i < NBK; i += 256) hist[i] = 0;
        __syncthreads();
        for (int i = tid; i < CH; i += 256) {
            int e = e0 + i;
            if (e < E) atomicAdd(&hist[row[e] >> 7], 1);
        }
        __syncthreads();
        for (int i = tid; i < NBK; i += 256) {
            int c = hist[i];
            base[i] = (c > 0) ? (i * BCAP + atomicAdd(&bcursor[i], c)) : 0;
            hist[i] = 0;
        }
        __syncthreads();
        for (int i = tid; i < CH; i += 256) {
            int e = e0 + i;
            if (e < E) {
                int r = row[e];
                int bk = r >> 7;
                int rk = atomicAdd(&hist[bk], 1);
                tmp[base[bk] + rk] = make_int2(((r & 127) << 16) | col[e],
                                               __float_as_int(vals[e]));
            }
        }
        return;
    }

    if (b < 978) {
        const int wave = tid >> 6;
        const int lane = tid & 63;
        const int ln15 = lane & 15;
        const int quad = lane >> 4;
        const int m0 = (b - 196) * 64;

        short8 bfr[4][2];
#pragma unroll
        for (int kc = 0; kc < 4; ++kc)
#pragma unroll
            for (int h = 0; h < 2; ++h)
#pragma unroll
                for (int j = 0; j < 8; ++j)
                    bfr[kc][h][j] = (short)f2bb(
                        W1[(size_t)(kc * 32 + quad * 8 + j) * 128 + (wave * 2 + h) * 16 + ln15]);

#pragma unroll
        for (int i = 0; i < 4; ++i) {
            int idx = tid + i * 256;
            int r = idx >> 4;
            int c8 = (idx & 15) * 8;
            uint4 pk = {0, 0, 0, 0};
            if (m0 + r < M) {
                const float* src = &x[(size_t)(m0 + r) * 128 + c8];
                float4 a = *(const float4*)src;
                float4 bq = *(const float4*)(src + 4);
                pk.x = f2bb(a.x) | ((unsigned int)f2bb(a.y) << 16);
                pk.y = f2bb(a.z) | ((unsigned int)f2bb(a.w) << 16);
                pk.z = f2bb(bq.x) | ((unsigned int)f2bb(bq.y) << 16);
                pk.w = f2bb(bq.z) | ((unsigned int)f2bb(bq.w) << 16);
            }
            *(uint4*)&As[r][c8] = pk;
        }
        __syncthreads();

        f32x4 acc[4][2];
#pragma unroll
        for (int s = 0; s < 4; ++s)
#pragma unroll
            for (int h = 0; h < 2; ++h) acc[s][h] = (f32x4){0.f, 0.f, 0.f, 0.f};
#pragma unroll
        for (int kc = 0; kc < 4; ++kc) {
            short8 af[4];
#pragma unroll
            for (int s = 0; s < 4; ++s)
                af[s] = *(const short8*)&As[s * 16 + ln15][kc * 32 + quad * 8];
#pragma unroll
            for (int s = 0; s < 4; ++s)
#pragma unroll
                for (int h = 0; h < 2; ++h)
                    acc[s][h] = __builtin_amdgcn_mfma_f32_16x16x32_bf16(
                        af[s], bfr[kc][h], acc[s][h], 0, 0, 0);
        }
#pragma unroll
        for (int s = 0; s < 4; ++s)
#pragma unroll
            for (int h = 0; h < 2; ++h) {
                int cl = (wave * 2 + h) * 16 + ln15;
#pragma unroll
                for (int r = 0; r < 4; ++r) {
                    int rw = m0 + s * 16 + quad * 4 + r;
                    if (rw < M)
                        support[(size_t)rw * 128 + cl] = __float2bfloat16(acc[s][h][r]);
                }
            }
        return;
    }

    int pb = b - 978;
    if (pb < 8)       pack_one(W2,  pW2,  128, 128, pb * 256 + tid);
    else if (pb < 16) pack_one(W3,  pW3,  128, 128, (pb - 8) * 256 + tid);
    else if (pb < 40) pack_one(fcW1, pfcW1, 384, 128, (pb - 16) * 256 + tid);
    else              pack_one(fcW2, pfcW2, 128, 64, (pb - 40) * 256 + tid);
}

// ---------------- CSR: per-bucket counting sort w/ 8-padding; fused bucket scan ----------------
__global__ __launch_bounds__(256)
void binB_kernel(const int2* __restrict__ tmp, const int* __restrict__ bcursor,
                 int2* __restrict__ rowrange, int2* __restrict__ epack, int N) {
    int b = blockIdx.x;
    int r0 = b << 7;
    int nr = N - r0; if (nr > 128) nr = 128;
    __shared__ int cnt[128];
    __shared__ int cur[128];
    __shared__ int rpos[128];
    __shared__ int red[256];
    int t = threadIdx.x;
    // fused exclusive scan: red[0] = sum_{i<b} bcursor[i]
    int partial = 0;
    for (int i = t; i < b; i += 256) partial += bcursor[i];
    red[t] = partial;
    if (t < 128) cnt[t] = 0;
    __syncthreads();
    for (int off = 128; off > 0; off >>= 1) {
        if (t < off) red[t] += red[t + off];
        __syncthreads();
    }
    int slab = b * BCAP;
    int send = slab + bcursor[b];
    for (int i = slab + t; i < send; i += 256)
        atomicAdd(&cnt[tmp[i].x >> 16], 1);
    __syncthreads();
    int rcnt = (t < 128) ? cnt[t] : 0;
    int pc = (rcnt + 7) & ~7;
    if (t < 128) cur[t] = pc;
    __syncthreads();
    for (int off = 1; off < 128; off <<= 1) {
        int u = (t >= off && t < 128) ? cur[t - off] : 0;
        __syncthreads();
        if (t < 128) cur[t] += u;
        __syncthreads();
    }
    int obase = red[0] + b * PADSLACK;
    if (t < 128) {
        int pos = obase + cur[t] - pc;
        rpos[t] = pos;
        cur[t] = pos;
        if (t < nr) rowrange[r0 + t] = make_int2(pos, pos + pc);
    }
    __syncthreads();
    for (int i = slab + t; i < send; i += 256) {
        int2 v = tmp[i];
        int rl = v.x >> 16;
        int c = v.x & 0xffff;
        int pos = atomicAdd(&cur[rl], 1);
        epack[pos] = make_int2(c, v.y);
    }
    if (t < 128) {
        int rc = rcnt;
        int pos = rpos[t];
#pragma unroll 1
        for (int i = pos + rc; i < pos + pc; ++i)
            epack[i] = make_int2(0, 0);
    }
}

// ---------------- shared aggregation helper ----------------
__device__ __forceinline__ void accum8(float* acc, long long e, uint4 u) {
    float f = __int_as_float((int)(e >> 32));
    acc[0] += f * b2f((unsigned short)(u.x & 0xffff));
    acc[1] += f * b2f((unsigned short)(u.x >> 16));
    acc[2] += f * b2f((unsigned short)(u.y & 0xffff));
    acc[3] += f * b2f((unsigned short)(u.y >> 16));
    acc[4] += f * b2f((unsigned short)(u.z & 0xffff));
    acc[5] += f * b2f((unsigned short)(u.z >> 16));
    acc[6] += f * b2f((unsigned short)(u.w & 0xffff));
    acc[7] += f * b2f((unsigned short)(u.w >> 16));
}

// Aggregate one node's row (128 cols as 4 groups x 16 lanes x 8 cols), returning
// per-lane 8 partial cols; wave split 4 groups of 16 lanes, dwordx4 gathers.
__device__ __forceinline__ void agg_node(const long long* __restrict__ ep,
                                         const __hip_bfloat16* __restrict__ support,
                                         int p, int end, int g, int j, float* acc) {
#pragma unroll
    for (int k = 0; k < 8; ++k) acc[k] = 0.f;
    long long e0 = 0, e1 = 0;
    uint4 u0 = {0, 0, 0, 0}, u1 = {0, 0, 0, 0};
    bool have = false;
    if (p < end) {
        e0 = ep[p + g];
        e1 = ep[p + 4 + g];
        u0 = *(const uint4*)&support[(size_t)(unsigned int)(e0 & 0xffffffffu) * 128 + j * 8];
        u1 = *(const uint4*)&support[(size_t)(unsigned int)(e1 & 0xffffffffu) * 128 + j * 8];
        p += 8;
        have = true;
    }
    while (p < end) {
        long long f0 = ep[p + g];
        long long f1 = ep[p + 4 + g];
        uint4 w0 = *(const uint4*)&support[(size_t)(unsigned int)(f0 & 0xffffffffu) * 128 + j * 8];
        uint4 w1 = *(const uint4*)&support[(size_t)(unsigned int)(f1 & 0xffffffffu) * 128 + j * 8];
        accum8(acc, e0, u0);
        accum8(acc, e1, u1);
        e0 = f0; u0 = w0; e1 = f1; u1 = w1;
        p += 8;
    }
    if (have) {
        accum8(acc, e0, u0);
        accum8(acc, e1, u1);
    }
    // combine the 4 edge-group partials: lanes {j, j+16, j+32, j+48} share cols
#pragma unroll
    for (int k = 0; k < 8; ++k) {
        acc[k] += __shfl_xor(acc[k], 16);
        acc[k] += __shfl_xor(acc[k], 32);
    }
}

// ---------------- fused SpMM (16 rows/block, 4 waves x 4 nodes) + next-layer GEMM ----------------
__global__ __launch_bounds__(256, 8)
void spmm_gemm_kernel(const int2* __restrict__ rowrange,
                      const int2* __restrict__ epack,
                      const __hip_bfloat16* __restrict__ support,
                      const float* __restrict__ bias,
                      __hip_bfloat16* __restrict__ gout,      // featb slice, ld 384
                      const __hip_bfloat16* __restrict__ pW,  // next layer packed W
                      __hip_bfloat16* __restrict__ Cout,      // next support, ld 128
                      int N) {
    __shared__ unsigned short As[16][136];
    const int tid = threadIdx.x;
    const int wv = tid >> 6;       // 0..3
    const int l = tid & 63;
    const int g = l >> 4;
    const int j = l & 15;
    const int m0 = blockIdx.x * 16;
    const long long* ep = (const long long*)epack;
    float4 b0 = *(const float4*)&bias[j * 8];
    float4 b1 = *(const float4*)&bias[j * 8 + 4];

    for (int i = 0; i < 4; ++i) {
        int node = m0 + wv * 4 + i;
        if (node < N) {
            int2 rr = rowrange[node];
            float acc[8];
            agg_node(ep, support, rr.x, rr.y, g, j, acc);
            if (g == 0) {
                unsigned int q0 = (unsigned int)f2bb(fmaxf(acc[0] + b0.x, 0.f))
                                | ((unsigned int)f2bb(fmaxf(acc[1] + b0.y, 0.f)) << 16);
                unsigned int q1 = (unsigned int)f2bb(fmaxf(acc[2] + b0.z, 0.f))
                                | ((unsigned int)f2bb(fmaxf(acc[3] + b0.w, 0.f)) << 16);
                unsigned int q2 = (unsigned int)f2bb(fmaxf(acc[4] + b1.x, 0.f))
                                | ((unsigned int)f2bb(fmaxf(acc[5] + b1.y, 0.f)) << 16);
                unsigned int q3 = (unsigned int)f2bb(fmaxf(acc[6] + b1.z, 0.f))
                                | ((unsigned int)f2bb(fmaxf(acc[7] + b1.w, 0.f)) << 16);
                uint4 st = {q0, q1, q2, q3};
                *(uint4*)&As[wv * 4 + i][j * 8] = st;
                *(uint4*)&gout[(size_t)node * 384 + j * 8] = st;
            }
        } else if (g == 0) {
            *(uint4*)&As[wv * 4 + i][j * 8] = (uint4){0, 0, 0, 0};
        }
    }
    __syncthreads();

    // ---- MFMA: Cout[m0:m0+16] = g @ W ; wave wv owns 16-col blocks {wv*2, wv*2+1} ----
    const int ln15 = l & 15;
    const int quad = l >> 4;
    f32x4 acc2[2];
    acc2[0] = (f32x4){0.f, 0.f, 0.f, 0.f};
    acc2[1] = (f32x4){0.f, 0.f, 0.f, 0.f};
#pragma unroll
    for (int kc = 0; kc < 4; ++kc) {
        short8 af = *(const short8*)&As[ln15][kc * 32 + quad * 8];
#pragma unroll
        for (int h = 0; h < 2; ++h) {
            int nt = wv * 2 + h;
            short8 bf = *(const short8*)&pW[((size_t)(nt * 4 + kc) * 64 + l) * 8];
            acc2[h] = __builtin_amdgcn_mfma_f32_16x16x32_bf16(af, bf, acc2[h], 0, 0, 0);
        }
    }
#pragma unroll
    for (int h = 0; h < 2; ++h) {
        int cl = (wv * 2 + h) * 16 + ln15;
#pragma unroll
        for (int r = 0; r < 4; ++r) {
            int rw = m0 + quad * 4 + r;
            if (rw < N)
                Cout[(size_t)rw * 128 + cl] = __float2bfloat16(acc2[h][r]);
        }
    }
}

// ---------------- fused SpMM (g3) + FC head, 16 rows/block ----------------
__global__ __launch_bounds__(256, 8)
void spmm_fc_kernel(const int2* __restrict__ rowrange,
                    const int2* __restrict__ epack,
                    const __hip_bfloat16* __restrict__ support,
                    const float* __restrict__ bias,           // b3
                    const __hip_bfloat16* __restrict__ featb, // g1|g2 (cols 0..255), ld 384
                    const __hip_bfloat16* __restrict__ pfcW1,
                    const float* __restrict__ fcb1,
                    const __hip_bfloat16* __restrict__ pfcW2,
                    const float* __restrict__ fcb2,
                    const float* __restrict__ fcW3, const float* __restrict__ fcb3,
                    float* __restrict__ out, int N) {
    __shared__ unsigned short As[16][136];
    __shared__ float w3s[128];
    __shared__ float b3s[2];
    const int tid = threadIdx.x;
    const int wv = tid >> 6;       // 0..3
    const int l = tid & 63;
    const int g = l >> 4;
    const int j = l & 15;
    const int m0 = blockIdx.x * 16;
    const long long* ep = (const long long*)epack;
    if (tid < 128) w3s[tid] = fcW3[tid];
    if (tid < 2) b3s[tid] = fcb3[tid];
    float4 b0 = *(const float4*)&bias[j * 8];
    float4 b1 = *(const float4*)&bias[j * 8 + 4];

    // ---- aggregate g3 into As only (g3 has no other consumer) ----
    for (int i = 0; i < 4; ++i) {
        int node = m0 + wv * 4 + i;
        if (node < N) {
            int2 rr = rowrange[node];
            float acc[8];
            agg_node(ep, support, rr.x, rr.y, g, j, acc);
            if (g == 0) {
                unsigned int q0 = (unsigned int)f2bb(fmaxf(acc[0] + b0.x, 0.f))
                                | ((unsigned int)f2bb(fmaxf(acc[1] + b0.y, 0.f)) << 16);
                unsigned int q1 = (unsigned int)f2bb(fmaxf(acc[2] + b0.z, 0.f))
                                | ((unsigned int)f2bb(fmaxf(acc[3] + b0.w, 0.f)) << 16);
                unsigned int q2 = (unsigned int)f2bb(fmaxf(acc[4] + b1.x, 0.f))
                                | ((unsigned int)f2bb(fmaxf(acc[5] + b1.y, 0.f)) << 16);
                unsigned int q3 = (unsigned int)f2bb(fmaxf(acc[6] + b1.z, 0.f))
                                | ((unsigned int)f2bb(fmaxf(acc[7] + b1.w, 0.f)) << 16);
                uint4 st = {q0, q1, q2, q3};
                *(uint4*)&As[wv * 4 + i][j * 8] = st;
            }
        } else if (g == 0) {
            *(uint4*)&As[wv * 4 + i][j * 8] = (uint4){0, 0, 0, 0};
        }
    }
    __syncthreads();

    // ---- fc1: feat @ fcW1 over kb in order {2 (g3, already in As), 0, 1} ----
    const int ln15 = l & 15;
    const int quad = l >> 4;
    f32x4 acc[2];
    acc[0] = (f32x4){0.f, 0.f, 0.f, 0.f};
    acc[1] = (f32x4){0.f, 0.f, 0.f, 0.f};
#pragma unroll
    for (int step = 0; step < 3; ++step) {
        const int kb = (step == 0) ? 2 : (step - 1);
        if (step != 0) {
            __syncthreads();   // previous MFMAs done reading As
            int r = tid >> 4;
            int c8 = (tid & 15) * 8;
            *(uint4*)&As[r][c8] =
                *(const uint4*)&featb[(size_t)(m0 + r) * 384 + kb * 128 + c8];
            __syncthreads();
        }
#pragma unroll
        for (int kc = 0; kc < 4; ++kc) {
            short8 af = *(const short8*)&As[ln15][kc * 32 + quad * 8];
            int kcg = kb * 4 + kc;
#pragma unroll
            for (int h = 0; h < 2; ++h) {
                int nt = wv * 2 + h;
                short8 bf = *(const short8*)&pfcW1[((size_t)(nt * 12 + kcg) * 64 + l) * 8];
                acc[h] = __builtin_amdgcn_mfma_f32_16x16x32_bf16(af, bf, acc[h], 0, 0, 0);
            }
        }
    }
    __syncthreads();
#pragma unroll
    for (int h = 0; h < 2; ++h) {
        int col = (wv * 2 + h) * 16 + ln15;
        float bv = fcb1[col];
#pragma unroll
        for (int r = 0; r < 4; ++r)
            As[quad * 4 + r][col] = f2bb(fmaxf(acc[h][r] + bv, 0.f));
    }
    __syncthreads();

    // ---- fc2: 128 -> 64, wave wv owns 16-col block wv ----
    f32x4 acc2 = (f32x4){0.f, 0.f, 0.f, 0.f};
#pragma unroll
    for (int kc = 0; kc < 4; ++kc) {
        short8 af = *(const short8*)&As[ln15][kc * 32 + quad * 8];
        short8 bfw = *(const short8*)&pfcW2[((size_t)(wv * 4 + kc) * 64 + l) * 8];
        acc2 = __builtin_amdgcn_mfma_f32_16x16x32_bf16(af, bfw, acc2, 0, 0, 0);
    }
    __syncthreads();           // all As reads done before overwrite
    {
        int col2 = wv * 16 + ln15;
        float bv = fcb2[col2];
#pragma unroll
        for (int r = 0; r < 4; ++r)
            As[quad * 4 + r][col2] = f2bb(fmaxf(acc2[r] + bv, 0.f));
    }
    __syncthreads();

    // ---- fc3: 64 -> 2 ----
    if (tid < 32) {
        int row = tid >> 1, cls = tid & 1;
        int grow = m0 + row;
        if (grow < N) {
            float a = b3s[cls];
#pragma unroll
            for (int k = 0; k < 64; ++k)
                a += b2f(As[row][k]) * w3s[k * 2 + cls];
            out[(size_t)grow * 2 + cls] = a;
        }
    }
}

extern "C" void kernel_launch(void* const* d_in, const int* in_sizes, int n_in,
                              void* d_out, int out_size, void* d_ws, size_t ws_size,
                              hipStream_t stream) {
    const int*   adj_row  = (const int*)d_in[0];
    const int*   adj_col  = (const int*)d_in[1];
    const float* adj_vals = (const float*)d_in[2];
    const float* x        = (const float*)d_in[3];
    const float* W1   = (const float*)d_in[5];
    const float* b1   = (const float*)d_in[6];
    const float* W2   = (const float*)d_in[7];
    const float* b2   = (const float*)d_in[8];
    const float* W3   = (const float*)d_in[9];
    const float* b3   = (const float*)d_in[10];
    const float* fcW1 = (const float*)d_in[11];
    const float* fcb1 = (const float*)d_in[12];
    const float* fcW2 = (const float*)d_in[13];
    const float* fcb2 = (const float*)d_in[14];
    const float* fcW3 = (const float*)d_in[15];
    const float* fcb3 = (const float*)d_in[16];
    float* out = (float*)d_out;

    const int N = N_NODES, E = N_EDGES;
    const int Mpad = 50048;
    const int EPAD = E + NBK * PADSLACK + 64;   // padded edge capacity

    char* p = (char*)d_ws;
    auto alloc = [&](size_t bytes) {
        char* q = p;
        p += (bytes + 255) & ~(size_t)255;
        return q;
    };
    __hip_bfloat16* featb    = (__hip_bfloat16*)alloc((size_t)Mpad * 384 * 2); // g1|g2|(unused g3)
    __hip_bfloat16* supportb = (__hip_bfloat16*)alloc((size_t)Mpad * 128 * 2);
    __hip_bfloat16* supportc = (__hip_bfloat16*)alloc((size_t)Mpad * 128 * 2);
    __hip_bfloat16* pW2   = (__hip_bfloat16*)alloc(16384 * 2);
    __hip_bfloat16* pW3   = (__hip_bfloat16*)alloc(16384 * 2);
    __hip_bfloat16* pfcW1 = (__hip_bfloat16*)alloc(49152 * 2);
    __hip_bfloat16* pfcW2 = (__hip_bfloat16*)alloc(8192 * 2);
    int2*  rowrange  = (int2*)alloc((size_t)(N + 1) * 8);
    int*   bcursor   = (int*)alloc((size_t)NBK * 4);
    int2*  epack     = (int2*)alloc((size_t)EPAD * 8);
    int2*  tmp       = (int2*)alloc((size_t)NBK * BCAP * 8);

    // ---- stage1: binA + gemm1 + weight packs in one launch ----
    hipMemsetAsync(bcursor, 0, (size_t)NBK * 4, stream);
    stage1_kernel<<<1022, 256, 0, stream>>>(adj_row, adj_col, adj_vals, bcursor, tmp, E,
                                            x, supportb, N,
                                            W1, W2, W3, fcW1, fcW2,
                                            pW2, pW3, pfcW1, pfcW2);
    binB_kernel<<<NBK, 256, 0, stream>>>(tmp, bcursor, rowrange, epack, N);

    const int fgrid = cdiv(N, 16);   // 3125 blocks: 12+/CU, tail-friendly

    // ---- F1: agg(support1)->g1 (featb) + gemm2 -> supportc ----
    spmm_gemm_kernel<<<fgrid, 256, 0, stream>>>(rowrange, epack, supportb, b1,
                                                featb + 0, pW2, supportc, N);
    // ---- F2: agg(support2)->g2 (featb+128) + gemm3 -> supportb ----
    spmm_gemm_kernel<<<fgrid, 256, 0, stream>>>(rowrange, epack, supportc, b2,
                                                featb + 128, pW3, supportb, N);
    // ---- F3: agg(support3)->g3 (LDS only) + FC head -> out ----
    spmm_fc_kernel<<<fgrid, 256, 0, stream>>>(rowrange, epack, supportb, b3,
                                              featb, pfcW1, fcb1, pfcW2, fcb2,
                                              fcW3, fcb3, out, N);
}